// Round 14
// baseline (207.860 us; speedup 1.0000x reference)
//
#include <hip/hip_runtime.h>
#include <math.h>

#define HB 64      // batch
#define HD 1024    // hidden / input dim
#define KSF 256    // K-slice per split-K block (front chain)
#define KSB 128    // K-slice (back chain)
#define XS 68      // padded LDS row stride (floats)

typedef float f32x4 __attribute__((ext_vector_type(4)));

// ---------------------------------------------------------------------------
// Split-K register-tiled GEMM slice with register prefetch (R10-exact):
//   P[b][m0+mj] = sum_{n=k0..k0+KS-1} X[b][n] * W[m][n]
// ---------------------------------------------------------------------------
template<int KS>
__device__ __forceinline__ void splitk_tile(
    const float* __restrict__ X0, int noff,
    const float* __restrict__ W, int K,
    int m0, int k0,
    float* __restrict__ P)
{
    __shared__ __align__(16) float Xs[32][XS];
    __shared__ __align__(16) float Ws[32][XS];
    const int t  = threadIdx.x;
    const int bx = t & 15;
    const int my = t >> 4;
    float acc[4][4] = {};

    float4 xp[2], wp[2];
    #pragma unroll
    for (int i = 0; i < 2; ++i) {
        int u = t + 256 * i;
        int r = u >> 3, nq = u & 7;
        xp[i] = *(const float4*)&X0[r * HD + (k0 - noff) + nq * 4];
        wp[i] = *(const float4*)&W[(long long)(m0 + r) * K + k0 + nq * 4];
    }

    for (int kc = 0; kc < KS; kc += 32) {
        #pragma unroll
        for (int i = 0; i < 2; ++i) {
            int u = t + 256 * i;
            int r = u >> 3, nq = u & 7;
            Xs[nq * 4 + 0][r] = xp[i].x; Xs[nq * 4 + 1][r] = xp[i].y;
            Xs[nq * 4 + 2][r] = xp[i].z; Xs[nq * 4 + 3][r] = xp[i].w;
            Ws[nq * 4 + 0][r] = wp[i].x; Ws[nq * 4 + 1][r] = wp[i].y;
            Ws[nq * 4 + 2][r] = wp[i].z; Ws[nq * 4 + 3][r] = wp[i].w;
        }
        __syncthreads();
        if (kc + 32 < KS) {
            const int n0 = k0 + kc + 32;
            #pragma unroll
            for (int i = 0; i < 2; ++i) {
                int u = t + 256 * i;
                int r = u >> 3, nq = u & 7;
                xp[i] = *(const float4*)&X0[r * HD + (n0 - noff) + nq * 4];
                wp[i] = *(const float4*)&W[(long long)(m0 + r) * K + n0 + nq * 4];
            }
        }
        #pragma unroll
        for (int n = 0; n < 32; ++n) {
            float4 xv = *(const float4*)&Xs[n][bx * 4];
            float4 wv = *(const float4*)&Ws[n][my * 4];
            float xe[4] = {xv.x, xv.y, xv.z, xv.w};
            float we[4] = {wv.x, wv.y, wv.z, wv.w};
            #pragma unroll
            for (int i = 0; i < 4; ++i)
                #pragma unroll
                for (int j = 0; j < 4; ++j)
                    acc[i][j] = fmaf(xe[i], we[j], acc[i][j]);
        }
        __syncthreads();
    }
    #pragma unroll
    for (int i = 0; i < 4; ++i) {
        float4 o4 = make_float4(acc[i][0], acc[i][1], acc[i][2], acc[i][3]);
        *(float4*)&P[(bx * 4 + i) * HD + m0 + my * 4] = o4;
    }
}

// ---------------------------------------------------------------------------
// Front chain, split-K GEMM with last-block-done fused reduce.
// grid (16 m-tiles, 28 gy units): gy 0..11 q/k/v (4 splits), 12..27 f/i (8).
// Slab bases: q=0, k=4, v=8, f=12, i=20.
// Counter trick: trigger on old%nsplit==nsplit-1 — works from ANY initial
// counter value (each launch adds exactly nsplit), so no reset needed.
// ---------------------------------------------------------------------------
__global__ __launch_bounds__(256) void qkvfi_fused(
    const float* __restrict__ x, const float* __restrict__ h,
    const float* __restrict__ Wq, const float* __restrict__ Wk,
    const float* __restrict__ Wv, const float* __restrict__ Wf,
    const float* __restrict__ Wi,
    const float* __restrict__ bq, const float* __restrict__ bk,
    const float* __restrict__ bv, const float* __restrict__ bfv,
    const float* __restrict__ biv,
    float* __restrict__ P,
    float* __restrict__ q, float* __restrict__ k, float* __restrict__ v,
    float* __restrict__ fg, float* __restrict__ ig,
    unsigned int* __restrict__ cnt)
{
    const int gy = blockIdx.y;
    const int mt = blockIdx.x;
    const int m0 = mt * 64;
    const float* W; int K, split, g;
    if (gy < 12) {
        g = gy >> 2; split = gy & 3; K = HD;
        W = (g == 0) ? Wq : (g == 1) ? Wk : Wv;
    } else {
        int tt = gy - 12; g = 3 + (tt >> 3); split = tt & 7; K = 2 * HD;
        W = (g == 4) ? Wi : Wf;
    }
    const int k0 = split * KSF;
    const float* X0; int noff;
    if (k0 < HD) { X0 = x; noff = 0; } else { X0 = h; noff = HD; }
    splitk_tile<KSF>(X0, noff, W, K, m0, k0, P + (size_t)gy * (HB * HD));

    // --- last-block-done reduce for this (gemm, m-tile) ---
    const int nsplit = (g < 3) ? 4 : 8;
    const int sb     = (g < 3) ? g * 4 : 12 + (g - 3) * 8;
    __threadfence();
    __shared__ unsigned int oldv;
    if (threadIdx.x == 0) oldv = atomicAdd(&cnt[g * 16 + mt], 1u);
    __syncthreads();
    if (oldv % nsplit != (unsigned)(nsplit - 1)) return;
    __threadfence();

    const float* bias; float* out; int act;
    switch (g) {
        case 0:  bias = bq;  out = q;  act = 0; break;
        case 1:  bias = bk;  out = k;  act = 0; break;
        case 2:  bias = bv;  out = v;  act = 0; break;
        case 3:  bias = bfv; out = fg; act = 1; break;
        default: bias = biv; out = ig; act = 1; break;
    }
    const float4* P4 = (const float4*)P;
    const int c0 = m0 / 4;     // first float4 column of this m-tile
    #pragma unroll
    for (int it = 0; it < 4; ++it) {
        const int u   = threadIdx.x + 256 * it;   // 0..1023
        const int b   = u >> 4;
        const int c   = u & 15;
        const int idx = b * 256 + c0 + c;
        float4 s = ((const float4*)bias)[c0 + c];
        for (int i = 0; i < nsplit; ++i) {
            float4 p = P4[(size_t)(sb + i) * 16384 + idx];
            s.x += p.x; s.y += p.y; s.z += p.z; s.w += p.w;
        }
        if (act) {
            s.x = 1.0f / (1.0f + expf(-s.x)); s.y = 1.0f / (1.0f + expf(-s.y));
            s.z = 1.0f / (1.0f + expf(-s.z)); s.w = 1.0f / (1.0f + expf(-s.w));
        }
        ((float4*)out)[idx] = s;
    }
}

// ---------------------------------------------------------------------------
// Back chain: out GEMM with last-block-done fused reduce (16 counters, mod 8).
// ---------------------------------------------------------------------------
__global__ __launch_bounds__(256) void out_fused(
    const float* __restrict__ tr, const float* __restrict__ Wo,
    const float* __restrict__ bo,
    float* __restrict__ P2, float* __restrict__ hnew,
    unsigned int* __restrict__ cnt)
{
    const int mt    = blockIdx.x;
    const int split = blockIdx.y;   // 0..7
    const int m0    = mt * 64;
    splitk_tile<KSB>(tr, 0, Wo, HD, m0, split * KSB,
                     P2 + (size_t)split * (HB * HD));

    __threadfence();
    __shared__ unsigned int oldv;
    if (threadIdx.x == 0) oldv = atomicAdd(&cnt[mt], 1u);
    __syncthreads();
    if (oldv % 8u != 7u) return;
    __threadfence();

    const float4* P4 = (const float4*)P2;
    const int c0 = m0 / 4;
    #pragma unroll
    for (int it = 0; it < 4; ++it) {
        const int u   = threadIdx.x + 256 * it;   // 0..1023
        const int b   = u >> 4;
        const int c   = u & 15;
        const int idx = b * 256 + c0 + c;
        float4 s = ((const float4*)bo)[c0 + c];
        #pragma unroll
        for (int i = 0; i < 8; ++i) {
            float4 p = P4[(size_t)i * 16384 + idx];
            s.x += p.x; s.y += p.y; s.z += p.z; s.w += p.w;
        }
        ((float4*)hnew)[idx] = s;
    }
}

// ---------------------------------------------------------------------------
// Fused C update + readout (R11-exact — best measured, NT-load/plain-store):
//   Cn[b,m,n] = f[b,m]*C[b,m,n] + (i[b,m]*k[b,m])*v[b,n]
//   tr[b,m]   = tanh( sum_n Cn[b,m,n] * q[b,n] )
// ---------------------------------------------------------------------------
__global__ __launch_bounds__(256) void update_kernel(
    const float* __restrict__ C,
    const float* __restrict__ q, const float* __restrict__ k,
    const float* __restrict__ v, const float* __restrict__ fg,
    const float* __restrict__ ig,
    float* __restrict__ Cn, float* __restrict__ tr)
{
    __shared__ __align__(16) float qs[HD];
    __shared__ __align__(16) float vs[HD];
    const int t    = threadIdx.x;
    const int wid  = t >> 6;
    const int lane = t & 63;
    const int row  = blockIdx.x * 4 + wid;      // 0 .. B*HD-1
    const int b    = row >> 10;                 // same for all 4 rows (4|1024)
    const int m    = row & (HD - 1);

    ((float4*)qs)[t] = ((const float4*)q)[b * 256 + t];
    ((float4*)vs)[t] = ((const float4*)v)[b * 256 + t];

    const float fm  = fg[b * HD + m];
    const float ikm = ig[b * HD + m] * k[b * HD + m];
    __syncthreads();

    const f32x4* C4 = (const f32x4*)C;
    const f32x4* V4 = (const f32x4*)vs;
    const f32x4* Q4 = (const f32x4*)qs;
    f32x4*       N4 = (f32x4*)Cn;

    const int base = row * (HD / 4);

    float racc = 0.f;
    #pragma unroll
    for (int j = 0; j < 4; ++j) {
        int o = lane + 64 * j;
        f32x4 c4 = __builtin_nontemporal_load(&C4[base + o]);
        f32x4 v4 = V4[o];
        f32x4 q4 = Q4[o];
        f32x4 cn;
        cn.x = fmaf(fm, c4.x, ikm * v4.x);
        cn.y = fmaf(fm, c4.y, ikm * v4.y);
        cn.z = fmaf(fm, c4.z, ikm * v4.z);
        cn.w = fmaf(fm, c4.w, ikm * v4.w);
        N4[base + o] = cn;                      // plain cached store
        racc += cn.x * q4.x + cn.y * q4.y + cn.z * q4.z + cn.w * q4.w;
    }
    #pragma unroll
    for (int off = 32; off; off >>= 1) racc += __shfl_xor(racc, off);
    if (lane == 0) tr[row] = tanhf(racc);
}

extern "C" void kernel_launch(void* const* d_in, const int* in_sizes, int n_in,
                              void* d_out, int out_size, void* d_ws, size_t ws_size,
                              hipStream_t stream) {
    const float* x  = (const float*)d_in[0];
    const float* h  = (const float*)d_in[1];
    const float* C  = (const float*)d_in[2];
    const float* Wq = (const float*)d_in[3];
    const float* bq = (const float*)d_in[4];
    const float* Wk = (const float*)d_in[5];
    const float* bk = (const float*)d_in[6];
    const float* Wv = (const float*)d_in[7];
    const float* bv = (const float*)d_in[8];
    const float* Wf = (const float*)d_in[9];
    const float* bf = (const float*)d_in[10];
    const float* Wi = (const float*)d_in[11];
    const float* bi = (const float*)d_in[12];
    const float* Wo = (const float*)d_in[13];
    const float* bo = (const float*)d_in[14];

    float* outp = (float*)d_out;
    float* hnew = outp;                    // [B,HD]
    float* Cn   = outp + HB * HD;          // [B,HD,HD]

    const size_t SL = (size_t)HB * HD;     // 65536
    float* ws = (float*)d_ws;
    float* q  = ws + 0 * SL;
    float* k  = ws + 1 * SL;
    float* v  = ws + 2 * SL;
    float* fg = ws + 3 * SL;
    float* ig = ws + 4 * SL;
    float* tr = ws + 5 * SL;
    float* P  = ws + 6 * SL;               // 28 slabs (KS=256)
    float* P2 = ws + 34 * SL;              // 8 slabs  (KS=128)
    unsigned int* cnt  = (unsigned int*)(ws + 42 * SL);   // 80 front counters
    unsigned int* cnt2 = cnt + 128;                       // 16 back counters

    qkvfi_fused<<<dim3(16, 28), 256, 0, stream>>>(
        x, h, Wq, Wk, Wv, Wf, Wi, bq, bk, bv, bf, bi,
        P, q, k, v, fg, ig, cnt);
    update_kernel<<<dim3((HB * HD) / 4), 256, 0, stream>>>(
        C, q, k, v, fg, ig, Cn, tr);
    out_fused<<<dim3(16, 8), 256, 0, stream>>>(tr, Wo, bo, P2, hnew, cnt2);
}

// Round 15
// 127.723 us; speedup vs baseline: 1.6274x; 1.6274x over previous
//
#include <hip/hip_runtime.h>
#include <math.h>

#define HB 64      // batch
#define HD 1024    // hidden / input dim
#define KSF 256    // K-slice per split-K block (front chain)
#define KSB 128    // K-slice (back chain)
#define XS 68      // padded LDS row stride (floats)

typedef float f32x4 __attribute__((ext_vector_type(4)));

// ---------------------------------------------------------------------------
// Split-K register-tiled GEMM slice with register prefetch (R10-exact):
//   P[b][m0+mj] = sum_{n=k0..k0+KS-1} X[b][n] * W[m][n]
// ---------------------------------------------------------------------------
template<int KS>
__device__ __forceinline__ void splitk_tile(
    const float* __restrict__ X0, int noff,
    const float* __restrict__ W, int K,
    int m0, int k0,
    float* __restrict__ P)
{
    __shared__ __align__(16) float Xs[32][XS];
    __shared__ __align__(16) float Ws[32][XS];
    const int t  = threadIdx.x;
    const int bx = t & 15;
    const int my = t >> 4;
    float acc[4][4] = {};

    float4 xp[2], wp[2];
    #pragma unroll
    for (int i = 0; i < 2; ++i) {
        int u = t + 256 * i;
        int r = u >> 3, nq = u & 7;
        xp[i] = *(const float4*)&X0[r * HD + (k0 - noff) + nq * 4];
        wp[i] = *(const float4*)&W[(long long)(m0 + r) * K + k0 + nq * 4];
    }

    for (int kc = 0; kc < KS; kc += 32) {
        #pragma unroll
        for (int i = 0; i < 2; ++i) {
            int u = t + 256 * i;
            int r = u >> 3, nq = u & 7;
            Xs[nq * 4 + 0][r] = xp[i].x; Xs[nq * 4 + 1][r] = xp[i].y;
            Xs[nq * 4 + 2][r] = xp[i].z; Xs[nq * 4 + 3][r] = xp[i].w;
            Ws[nq * 4 + 0][r] = wp[i].x; Ws[nq * 4 + 1][r] = wp[i].y;
            Ws[nq * 4 + 2][r] = wp[i].z; Ws[nq * 4 + 3][r] = wp[i].w;
        }
        __syncthreads();
        if (kc + 32 < KS) {
            const int n0 = k0 + kc + 32;
            #pragma unroll
            for (int i = 0; i < 2; ++i) {
                int u = t + 256 * i;
                int r = u >> 3, nq = u & 7;
                xp[i] = *(const float4*)&X0[r * HD + (n0 - noff) + nq * 4];
                wp[i] = *(const float4*)&W[(long long)(m0 + r) * K + n0 + nq * 4];
            }
        }
        #pragma unroll
        for (int n = 0; n < 32; ++n) {
            float4 xv = *(const float4*)&Xs[n][bx * 4];
            float4 wv = *(const float4*)&Ws[n][my * 4];
            float xe[4] = {xv.x, xv.y, xv.z, xv.w};
            float we[4] = {wv.x, wv.y, wv.z, wv.w};
            #pragma unroll
            for (int i = 0; i < 4; ++i)
                #pragma unroll
                for (int j = 0; j < 4; ++j)
                    acc[i][j] = fmaf(xe[i], we[j], acc[i][j]);
        }
        __syncthreads();
    }
    #pragma unroll
    for (int i = 0; i < 4; ++i) {
        float4 o4 = make_float4(acc[i][0], acc[i][1], acc[i][2], acc[i][3]);
        *(float4*)&P[(bx * 4 + i) * HD + m0 + my * 4] = o4;
    }
}

// grid.x = 16 m-tiles; grid.y = 28 (gemm,split) units, KS=256:
//   gy 0..11 : q/k/v (4 splits each); gy 12..27 : f/i (8 splits each)
__global__ __launch_bounds__(256) void qkvfi_splitk(
    const float* __restrict__ x, const float* __restrict__ h,
    const float* __restrict__ Wq, const float* __restrict__ Wk,
    const float* __restrict__ Wv, const float* __restrict__ Wf,
    const float* __restrict__ Wi, float* __restrict__ P)
{
    const int gy = blockIdx.y;
    const float* W; int K, split;
    if (gy < 12) {
        int g = gy >> 2; split = gy & 3; K = HD;
        W = (g == 0) ? Wq : (g == 1) ? Wk : Wv;
    } else {
        int tt = gy - 12; int g = tt >> 3; split = tt & 7; K = 2 * HD;
        W = g ? Wi : Wf;
    }
    const int k0 = split * KSF;
    const float* X0; int noff;
    if (k0 < HD) { X0 = x; noff = 0; } else { X0 = h; noff = HD; }
    splitk_tile<KSF>(X0, noff, W, K, blockIdx.x * 64, k0,
                     P + (size_t)gy * (HB * HD));
}

__global__ __launch_bounds__(256) void out_splitk(
    const float* __restrict__ tr, const float* __restrict__ Wo,
    float* __restrict__ P2)
{
    const int split = blockIdx.y;   // 0..7
    splitk_tile<KSB>(tr, 0, Wo, HD, blockIdx.x * 64, split * KSB,
                     P2 + (size_t)split * (HB * HD));
}

// Deterministic float4 partial reduction + bias + activation for q/k/v/f/i.
// Slab bases (KS=256): q=0(ns4), k=4(ns4), v=8(ns4), f=12(ns8), i=20(ns8).
__global__ __launch_bounds__(256) void reduce_qkvfi(
    const float* __restrict__ P,
    const float* __restrict__ bq, const float* __restrict__ bk,
    const float* __restrict__ bv, const float* __restrict__ bfv,
    const float* __restrict__ biv,
    float* __restrict__ q, float* __restrict__ k, float* __restrict__ v,
    float* __restrict__ fg, float* __restrict__ ig)
{
    const int o4 = blockIdx.x * 256 + threadIdx.x;   // float4 units, 0..81919
    const int g  = o4 >> 14;
    const int r4 = o4 & 16383;
    const int m4 = r4 & 255;
    int base, ns, act; const float* bias; float* out;
    switch (g) {
        case 0:  base = 0;  ns = 4; bias = bq;  out = q;  act = 0; break;
        case 1:  base = 4;  ns = 4; bias = bk;  out = k;  act = 0; break;
        case 2:  base = 8;  ns = 4; bias = bv;  out = v;  act = 0; break;
        case 3:  base = 12; ns = 8; bias = bfv; out = fg; act = 1; break;
        default: base = 20; ns = 8; bias = biv; out = ig; act = 1; break;
    }
    float4 s = ((const float4*)bias)[m4];
    const float4* P4 = (const float4*)P;
    for (int i = 0; i < ns; ++i) {
        float4 p = P4[(size_t)(base + i) * 16384 + r4];
        s.x += p.x; s.y += p.y; s.z += p.z; s.w += p.w;
    }
    if (act) {
        s.x = 1.0f / (1.0f + expf(-s.x)); s.y = 1.0f / (1.0f + expf(-s.y));
        s.z = 1.0f / (1.0f + expf(-s.z)); s.w = 1.0f / (1.0f + expf(-s.w));
    }
    ((float4*)out)[r4] = s;
}

__global__ __launch_bounds__(256) void reduce_out(
    const float* __restrict__ P2, const float* __restrict__ bo,
    float* __restrict__ hnew)
{
    const int o4 = blockIdx.x * 256 + threadIdx.x;   // 0..16383
    const int m4 = o4 & 255;
    float4 s = ((const float4*)bo)[m4];
    const float4* P4 = (const float4*)P2;
    #pragma unroll
    for (int i = 0; i < 8; ++i) {
        float4 p = P4[(size_t)i * 16384 + o4];
        s.x += p.x; s.y += p.y; s.z += p.z; s.w += p.w;
    }
    ((float4*)hnew)[o4] = s;
}

// ---------------------------------------------------------------------------
// Fused C update + readout. R11 per-wave pattern EXACTLY (1 row/wave, NT
// C-load, plain Cn store, o = lane+64j, LDS q/v); SINGLE delta vs R11:
// 512 threads / 8 rows per block — q/v staging traffic and barriers halve
// (waves 0..3 stage q, 4..7 stage v; 4 blocks/CU keeps 32 waves/CU).
//   Cn[b,m,n] = f[b,m]*C[b,m,n] + (i[b,m]*k[b,m])*v[b,n]
//   tr[b,m]   = tanh( sum_n Cn[b,m,n] * q[b,n] )
// ---------------------------------------------------------------------------
__global__ __launch_bounds__(512) void update_kernel(
    const float* __restrict__ C,
    const float* __restrict__ q, const float* __restrict__ k,
    const float* __restrict__ v, const float* __restrict__ fg,
    const float* __restrict__ ig,
    float* __restrict__ Cn, float* __restrict__ tr)
{
    __shared__ __align__(16) float qs[HD];
    __shared__ __align__(16) float vs[HD];
    const int t    = threadIdx.x;
    const int wid  = t >> 6;                    // 0..7
    const int lane = t & 63;
    const int row  = blockIdx.x * 8 + wid;      // 0 .. B*HD-1
    const int b    = row >> 10;                 // same for all 8 rows (8|1024)
    const int m    = row & (HD - 1);

    // stage q[b,:] (threads 0..255) and v[b,:] (threads 256..511)
    if (t < 256)       ((float4*)qs)[t]       = ((const float4*)q)[b * 256 + t];
    else               ((float4*)vs)[t - 256] = ((const float4*)v)[b * 256 + (t - 256)];

    const float fm  = fg[b * HD + m];
    const float ikm = ig[b * HD + m] * k[b * HD + m];
    __syncthreads();

    const f32x4* C4 = (const f32x4*)C;
    const f32x4* V4 = (const f32x4*)vs;
    const f32x4* Q4 = (const f32x4*)qs;
    f32x4*       N4 = (f32x4*)Cn;

    const int base = row * (HD / 4);

    float racc = 0.f;
    #pragma unroll
    for (int j = 0; j < 4; ++j) {
        int o = lane + 64 * j;
        f32x4 c4 = __builtin_nontemporal_load(&C4[base + o]);
        f32x4 v4 = V4[o];
        f32x4 q4 = Q4[o];
        f32x4 cn;
        cn.x = fmaf(fm, c4.x, ikm * v4.x);
        cn.y = fmaf(fm, c4.y, ikm * v4.y);
        cn.z = fmaf(fm, c4.z, ikm * v4.z);
        cn.w = fmaf(fm, c4.w, ikm * v4.w);
        N4[base + o] = cn;                      // plain cached store
        racc += cn.x * q4.x + cn.y * q4.y + cn.z * q4.z + cn.w * q4.w;
    }
    #pragma unroll
    for (int off = 32; off; off >>= 1) racc += __shfl_xor(racc, off);
    if (lane == 0) tr[row] = tanhf(racc);
}

extern "C" void kernel_launch(void* const* d_in, const int* in_sizes, int n_in,
                              void* d_out, int out_size, void* d_ws, size_t ws_size,
                              hipStream_t stream) {
    const float* x  = (const float*)d_in[0];
    const float* h  = (const float*)d_in[1];
    const float* C  = (const float*)d_in[2];
    const float* Wq = (const float*)d_in[3];
    const float* bq = (const float*)d_in[4];
    const float* Wk = (const float*)d_in[5];
    const float* bk = (const float*)d_in[6];
    const float* Wv = (const float*)d_in[7];
    const float* bv = (const float*)d_in[8];
    const float* Wf = (const float*)d_in[9];
    const float* bf = (const float*)d_in[10];
    const float* Wi = (const float*)d_in[11];
    const float* bi = (const float*)d_in[12];
    const float* Wo = (const float*)d_in[13];
    const float* bo = (const float*)d_in[14];

    float* outp = (float*)d_out;
    float* hnew = outp;                    // [B,HD]
    float* Cn   = outp + HB * HD;          // [B,HD,HD]

    const size_t SL = (size_t)HB * HD;     // 65536
    float* ws = (float*)d_ws;
    float* q  = ws + 0 * SL;
    float* k  = ws + 1 * SL;
    float* v  = ws + 2 * SL;
    float* fg = ws + 3 * SL;
    float* ig = ws + 4 * SL;
    float* tr = ws + 5 * SL;
    float* P  = ws + 6 * SL;               // 28 slabs (KS=256)
    float* P2 = ws + 34 * SL;              // 8 slabs  (KS=128)

    qkvfi_splitk<<<dim3(16, 28), 256, 0, stream>>>(x, h, Wq, Wk, Wv, Wf, Wi, P);
    reduce_qkvfi<<<dim3(320), 256, 0, stream>>>(P, bq, bk, bv, bf, bi,
                                                q, k, v, fg, ig);
    update_kernel<<<dim3((HB * HD) / 8), 512, 0, stream>>>(
        C, q, k, v, fg, ig, Cn, tr);
    out_splitk<<<dim3(16, 8), 256, 0, stream>>>(tr, Wo, P2);
    reduce_out<<<dim3(64), 256, 0, stream>>>(P2, bo, hnew);
}

// Round 16
// 125.345 us; speedup vs baseline: 1.6583x; 1.0190x over previous
//
#include <hip/hip_runtime.h>
#include <math.h>

#define HB 64      // batch
#define HD 1024    // hidden / input dim
#define KSF 256    // K-slice per split-K block (front chain)
#define KSB 128    // K-slice (back chain)
#define XS 68      // padded LDS row stride (floats)

typedef float f32x4 __attribute__((ext_vector_type(4)));

// ---------------------------------------------------------------------------
// Split-K register-tiled GEMM slice with register prefetch (R10-exact):
//   P[b][m0+mj] = sum_{n=k0..k0+KS-1} X[b][n] * W[m][n]
// ---------------------------------------------------------------------------
template<int KS>
__device__ __forceinline__ void splitk_tile(
    const float* __restrict__ X0, int noff,
    const float* __restrict__ W, int K,
    int m0, int k0,
    float* __restrict__ P)
{
    __shared__ __align__(16) float Xs[32][XS];
    __shared__ __align__(16) float Ws[32][XS];
    const int t  = threadIdx.x;
    const int bx = t & 15;
    const int my = t >> 4;
    float acc[4][4] = {};

    float4 xp[2], wp[2];
    #pragma unroll
    for (int i = 0; i < 2; ++i) {
        int u = t + 256 * i;
        int r = u >> 3, nq = u & 7;
        xp[i] = *(const float4*)&X0[r * HD + (k0 - noff) + nq * 4];
        wp[i] = *(const float4*)&W[(long long)(m0 + r) * K + k0 + nq * 4];
    }

    for (int kc = 0; kc < KS; kc += 32) {
        #pragma unroll
        for (int i = 0; i < 2; ++i) {
            int u = t + 256 * i;
            int r = u >> 3, nq = u & 7;
            Xs[nq * 4 + 0][r] = xp[i].x; Xs[nq * 4 + 1][r] = xp[i].y;
            Xs[nq * 4 + 2][r] = xp[i].z; Xs[nq * 4 + 3][r] = xp[i].w;
            Ws[nq * 4 + 0][r] = wp[i].x; Ws[nq * 4 + 1][r] = wp[i].y;
            Ws[nq * 4 + 2][r] = wp[i].z; Ws[nq * 4 + 3][r] = wp[i].w;
        }
        __syncthreads();
        if (kc + 32 < KS) {
            const int n0 = k0 + kc + 32;
            #pragma unroll
            for (int i = 0; i < 2; ++i) {
                int u = t + 256 * i;
                int r = u >> 3, nq = u & 7;
                xp[i] = *(const float4*)&X0[r * HD + (n0 - noff) + nq * 4];
                wp[i] = *(const float4*)&W[(long long)(m0 + r) * K + n0 + nq * 4];
            }
        }
        #pragma unroll
        for (int n = 0; n < 32; ++n) {
            float4 xv = *(const float4*)&Xs[n][bx * 4];
            float4 wv = *(const float4*)&Ws[n][my * 4];
            float xe[4] = {xv.x, xv.y, xv.z, xv.w};
            float we[4] = {wv.x, wv.y, wv.z, wv.w};
            #pragma unroll
            for (int i = 0; i < 4; ++i)
                #pragma unroll
                for (int j = 0; j < 4; ++j)
                    acc[i][j] = fmaf(xe[i], we[j], acc[i][j]);
        }
        __syncthreads();
    }
    #pragma unroll
    for (int i = 0; i < 4; ++i) {
        float4 o4 = make_float4(acc[i][0], acc[i][1], acc[i][2], acc[i][3]);
        *(float4*)&P[(bx * 4 + i) * HD + m0 + my * 4] = o4;
    }
}

// grid.x = 16 m-tiles; grid.y = 28 (gemm,split) units, KS=256:
//   gy 0..11 : q/k/v (4 splits each); gy 12..27 : f/i (8 splits each)
__global__ __launch_bounds__(256) void qkvfi_splitk(
    const float* __restrict__ x, const float* __restrict__ h,
    const float* __restrict__ Wq, const float* __restrict__ Wk,
    const float* __restrict__ Wv, const float* __restrict__ Wf,
    const float* __restrict__ Wi, float* __restrict__ P)
{
    const int gy = blockIdx.y;
    const float* W; int K, split;
    if (gy < 12) {
        int g = gy >> 2; split = gy & 3; K = HD;
        W = (g == 0) ? Wq : (g == 1) ? Wk : Wv;
    } else {
        int tt = gy - 12; int g = tt >> 3; split = tt & 7; K = 2 * HD;
        W = g ? Wi : Wf;
    }
    const int k0 = split * KSF;
    const float* X0; int noff;
    if (k0 < HD) { X0 = x; noff = 0; } else { X0 = h; noff = HD; }
    splitk_tile<KSF>(X0, noff, W, K, blockIdx.x * 64, k0,
                     P + (size_t)gy * (HB * HD));
}

__global__ __launch_bounds__(256) void out_splitk(
    const float* __restrict__ tr, const float* __restrict__ Wo,
    float* __restrict__ P2)
{
    const int split = blockIdx.y;   // 0..7
    splitk_tile<KSB>(tr, 0, Wo, HD, blockIdx.x * 64, split * KSB,
                     P2 + (size_t)split * (HB * HD));
}

// Deterministic float4 partial reduction + bias + activation for q/k/v/f/i.
// Slab bases (KS=256): q=0(ns4), k=4(ns4), v=8(ns4), f=12(ns8), i=20(ns8).
__global__ __launch_bounds__(256) void reduce_qkvfi(
    const float* __restrict__ P,
    const float* __restrict__ bq, const float* __restrict__ bk,
    const float* __restrict__ bv, const float* __restrict__ bfv,
    const float* __restrict__ biv,
    float* __restrict__ q, float* __restrict__ k, float* __restrict__ v,
    float* __restrict__ fg, float* __restrict__ ig)
{
    const int o4 = blockIdx.x * 256 + threadIdx.x;   // float4 units, 0..81919
    const int g  = o4 >> 14;
    const int r4 = o4 & 16383;
    const int m4 = r4 & 255;
    int base, ns, act; const float* bias; float* out;
    switch (g) {
        case 0:  base = 0;  ns = 4; bias = bq;  out = q;  act = 0; break;
        case 1:  base = 4;  ns = 4; bias = bk;  out = k;  act = 0; break;
        case 2:  base = 8;  ns = 4; bias = bv;  out = v;  act = 0; break;
        case 3:  base = 12; ns = 8; bias = bfv; out = fg; act = 1; break;
        default: base = 20; ns = 8; bias = biv; out = ig; act = 1; break;
    }
    float4 s = ((const float4*)bias)[m4];
    const float4* P4 = (const float4*)P;
    for (int i = 0; i < ns; ++i) {
        float4 p = P4[(size_t)(base + i) * 16384 + r4];
        s.x += p.x; s.y += p.y; s.z += p.z; s.w += p.w;
    }
    if (act) {
        s.x = 1.0f / (1.0f + expf(-s.x)); s.y = 1.0f / (1.0f + expf(-s.y));
        s.z = 1.0f / (1.0f + expf(-s.z)); s.w = 1.0f / (1.0f + expf(-s.w));
    }
    ((float4*)out)[r4] = s;
}

__global__ __launch_bounds__(256) void reduce_out(
    const float* __restrict__ P2, const float* __restrict__ bo,
    float* __restrict__ hnew)
{
    const int o4 = blockIdx.x * 256 + threadIdx.x;   // 0..16383
    const int m4 = o4 & 255;
    float4 s = ((const float4*)bo)[m4];
    const float4* P4 = (const float4*)P2;
    #pragma unroll
    for (int i = 0; i < 8; ++i) {
        float4 p = P4[(size_t)i * 16384 + o4];
        s.x += p.x; s.y += p.y; s.z += p.z; s.w += p.w;
    }
    ((float4*)hnew)[o4] = s;
}

// ---------------------------------------------------------------------------
// Fused C update + readout (R11-exact — measured optimum of the full
// single-variable sweep: 1 row/wave, 256 thr, NT C-load, PLAIN Cn store,
// LDS-staged q/v, interleaved load/compute/store, o = lane+64j):
//   Cn[b,m,n] = f[b,m]*C[b,m,n] + (i[b,m]*k[b,m])*v[b,n]
//   tr[b,m]   = tanh( sum_n Cn[b,m,n] * q[b,n] )
// ---------------------------------------------------------------------------
__global__ __launch_bounds__(256) void update_kernel(
    const float* __restrict__ C,
    const float* __restrict__ q, const float* __restrict__ k,
    const float* __restrict__ v, const float* __restrict__ fg,
    const float* __restrict__ ig,
    float* __restrict__ Cn, float* __restrict__ tr)
{
    __shared__ __align__(16) float qs[HD];
    __shared__ __align__(16) float vs[HD];
    const int t    = threadIdx.x;
    const int wid  = t >> 6;
    const int lane = t & 63;
    const int row  = blockIdx.x * 4 + wid;      // 0 .. B*HD-1
    const int b    = row >> 10;                 // same for all 4 rows (4|1024)
    const int m    = row & (HD - 1);

    ((float4*)qs)[t] = ((const float4*)q)[b * 256 + t];
    ((float4*)vs)[t] = ((const float4*)v)[b * 256 + t];

    const float fm  = fg[b * HD + m];
    const float ikm = ig[b * HD + m] * k[b * HD + m];
    __syncthreads();

    const f32x4* C4 = (const f32x4*)C;
    const f32x4* V4 = (const f32x4*)vs;
    const f32x4* Q4 = (const f32x4*)qs;
    f32x4*       N4 = (f32x4*)Cn;

    const int base = row * (HD / 4);

    float racc = 0.f;
    #pragma unroll
    for (int j = 0; j < 4; ++j) {
        int o = lane + 64 * j;
        f32x4 c4 = __builtin_nontemporal_load(&C4[base + o]);
        f32x4 v4 = V4[o];
        f32x4 q4 = Q4[o];
        f32x4 cn;
        cn.x = fmaf(fm, c4.x, ikm * v4.x);
        cn.y = fmaf(fm, c4.y, ikm * v4.y);
        cn.z = fmaf(fm, c4.z, ikm * v4.z);
        cn.w = fmaf(fm, c4.w, ikm * v4.w);
        N4[base + o] = cn;                      // plain cached store
        racc += cn.x * q4.x + cn.y * q4.y + cn.z * q4.z + cn.w * q4.w;
    }
    #pragma unroll
    for (int off = 32; off; off >>= 1) racc += __shfl_xor(racc, off);
    if (lane == 0) tr[row] = tanhf(racc);
}

extern "C" void kernel_launch(void* const* d_in, const int* in_sizes, int n_in,
                              void* d_out, int out_size, void* d_ws, size_t ws_size,
                              hipStream_t stream) {
    const float* x  = (const float*)d_in[0];
    const float* h  = (const float*)d_in[1];
    const float* C  = (const float*)d_in[2];
    const float* Wq = (const float*)d_in[3];
    const float* bq = (const float*)d_in[4];
    const float* Wk = (const float*)d_in[5];
    const float* bk = (const float*)d_in[6];
    const float* Wv = (const float*)d_in[7];
    const float* bv = (const float*)d_in[8];
    const float* Wf = (const float*)d_in[9];
    const float* bf = (const float*)d_in[10];
    const float* Wi = (const float*)d_in[11];
    const float* bi = (const float*)d_in[12];
    const float* Wo = (const float*)d_in[13];
    const float* bo = (const float*)d_in[14];

    float* outp = (float*)d_out;
    float* hnew = outp;                    // [B,HD]
    float* Cn   = outp + HB * HD;          // [B,HD,HD]

    const size_t SL = (size_t)HB * HD;     // 65536
    float* ws = (float*)d_ws;
    float* q  = ws + 0 * SL;
    float* k  = ws + 1 * SL;
    float* v  = ws + 2 * SL;
    float* fg = ws + 3 * SL;
    float* ig = ws + 4 * SL;
    float* tr = ws + 5 * SL;
    float* P  = ws + 6 * SL;               // 28 slabs (KS=256)
    float* P2 = ws + 34 * SL;              // 8 slabs  (KS=128)

    qkvfi_splitk<<<dim3(16, 28), 256, 0, stream>>>(x, h, Wq, Wk, Wv, Wf, Wi, P);
    reduce_qkvfi<<<dim3(320), 256, 0, stream>>>(P, bq, bk, bv, bf, bi,
                                                q, k, v, fg, ig);
    update_kernel<<<dim3((HB * HD) / 4), 256, 0, stream>>>(
        C, q, k, v, fg, ig, Cn, tr);
    out_splitk<<<dim3(16, 8), 256, 0, stream>>>(tr, Wo, P2);
    reduce_out<<<dim3(64), 256, 0, stream>>>(P2, bo, hnew);
}